// Round 2
// baseline (1027.991 us; speedup 1.0000x reference)
//
#include <hip/hip_runtime.h>

#define IN_DIM 4096
#define OUT_DIM 4096
#define M_DIM 8192
#define RANK 32

typedef __bf16 bf16x8 __attribute__((ext_vector_type(8)));
typedef float f32x4 __attribute__((ext_vector_type(4)));

__device__ __forceinline__ unsigned short f2bf(float f) {
  unsigned u = __builtin_bit_cast(unsigned, f);
  u += 0x7FFF + ((u >> 16) & 1);   // round-to-nearest-even
  return (unsigned short)(u >> 16);
}

// ---------------- prep 1: x f32 -> bf16 ----------------
__global__ void prep_x_kernel(const float* __restrict__ X,
                              unsigned short* __restrict__ Xb) {
  const int stride = gridDim.x * blockDim.x;
  const int total4 = (M_DIM * IN_DIM) / 4;
  for (int i = blockIdx.x * blockDim.x + threadIdx.x; i < total4; i += stride) {
    const float4 v = reinterpret_cast<const float4*>(X)[i];
    ushort4 o;
    o.x = f2bf(v.x); o.y = f2bf(v.y); o.z = f2bf(v.z); o.w = f2bf(v.w);
    reinterpret_cast<ushort4*>(Xb)[i] = o;
  }
}

// ---------------- prep 2: w_eff = bf16(W + A @ B^T) ----------------
// grid (256, 8): block = 16 out-rows x 512 k-cols; ALPHA/R == 1.
__global__ void prep_w_kernel(const float* __restrict__ W,
                              const float* __restrict__ A,
                              const float* __restrict__ B,
                              unsigned short* __restrict__ Wb) {
  __shared__ float sA[16][RANK];
  const int tid = threadIdx.x;
  const int nb = blockIdx.x * 16;
  for (int i = tid; i < 16 * RANK; i += 256) sA[i >> 5][i & 31] = A[nb * RANK + i];
  __syncthreads();
#pragma unroll
  for (int half = 0; half < 2; ++half) {
    const int k = blockIdx.y * 512 + half * 256 + tid;
    float b[RANK];
    const float4* Bv = reinterpret_cast<const float4*>(B + (size_t)k * RANK);
#pragma unroll
    for (int r4 = 0; r4 < RANK / 4; ++r4) {
      const float4 v = Bv[r4];
      b[r4 * 4 + 0] = v.x; b[r4 * 4 + 1] = v.y;
      b[r4 * 4 + 2] = v.z; b[r4 * 4 + 3] = v.w;
    }
#pragma unroll
    for (int nn = 0; nn < 16; ++nn) {
      float d = 0.f;
#pragma unroll
      for (int r = 0; r < RANK; ++r) d += sA[nn][r] * b[r];
      const size_t idx = (size_t)(nb + nn) * IN_DIM + k;
      Wb[idx] = f2bf(W[idx] + d);
    }
  }
}

// ---------------- main GEMM: Y[M][N] = Xb[M][K] * Wb[N][K]^T + bias ----------------
// 128x128 tile, BK=64, 4 waves (2x2), each wave 64x64 via 4x4 frags of 16x16x32 MFMA.
// LDS XOR-swizzle: logical (row, kc) chunk (16B, kc=k>>3) stored at physical
// chunk row*8 + (kc ^ (row&7)).  Properties:
//  - staging: 8 consecutive lanes cover one row's 8 chunks (permuted) -> each
//    8-lane group reads one contiguous 128B global segment (coalesced);
//  - ds_read_b128 fragment read: bank-quad = kc ^ (li&7), distinct within every
//    aligned 8-lane group -> conflict-free;
//  - global_load_lds dest stays linear (wave-uniform base + lane*16), rule #21.
__global__ __launch_bounds__(256) void gemm_kernel(
    const unsigned short* __restrict__ Xb, const unsigned short* __restrict__ Wb,
    const float* __restrict__ bias, float* __restrict__ Y) {
  __shared__ unsigned short sA[128 * 64];   // 16 KB
  __shared__ unsigned short sB[128 * 64];   // 16 KB
  const int tid  = threadIdx.x;
  const int lane = tid & 63;
  const int wid  = tid >> 6;
  const int wr   = wid >> 1, wc = wid & 1;
  const int li   = lane & 15, kg = lane >> 4;

  // XCD-aware bijective swizzle: 2048 blocks = 8 XCDs x 256
  const int bid = blockIdx.x;
  const int swz = (bid & 7) * 256 + (bid >> 3);
  const int bx  = swz & 31;    // N tile index (OUT/128 = 32)
  const int by  = swz >> 5;    // M tile index (M/128 = 64)
  const int bRow = by * 128;
  const int bCol = bx * 128;

  f32x4 acc[4][4];
#pragma unroll
  for (int m = 0; m < 4; ++m)
#pragma unroll
    for (int n = 0; n < 4; ++n) acc[m][n] = f32x4{0.f, 0.f, 0.f, 0.f};

  // staging source per thread per slot t: physical chunk p = t*256 + tid,
  // row = p>>3, logical kc = (p&7) ^ (row&7)
  const int p0 = tid, r_0 = p0 >> 3, kc_0 = (p0 & 7) ^ (r_0 & 7);
  const int p1 = 256 + tid, r_1 = p1 >> 3, kc_1 = (p1 & 7) ^ (r_1 & 7);
  const int p2 = 512 + tid, r_2 = p2 >> 3, kc_2 = (p2 & 7) ^ (r_2 & 7);
  const int p3 = 768 + tid, r_3 = p3 >> 3, kc_3 = (p3 & 7) ^ (r_3 & 7);

  const unsigned short* gA0 = Xb + (size_t)(bRow + r_0) * IN_DIM + kc_0 * 8;
  const unsigned short* gA1 = Xb + (size_t)(bRow + r_1) * IN_DIM + kc_1 * 8;
  const unsigned short* gA2 = Xb + (size_t)(bRow + r_2) * IN_DIM + kc_2 * 8;
  const unsigned short* gA3 = Xb + (size_t)(bRow + r_3) * IN_DIM + kc_3 * 8;
  const unsigned short* gB0 = Wb + (size_t)(bCol + r_0) * IN_DIM + kc_0 * 8;
  const unsigned short* gB1 = Wb + (size_t)(bCol + r_1) * IN_DIM + kc_1 * 8;
  const unsigned short* gB2 = Wb + (size_t)(bCol + r_2) * IN_DIM + kc_2 * 8;
  const unsigned short* gB3 = Wb + (size_t)(bCol + r_3) * IN_DIM + kc_3 * 8;

  char* const ldsA = (char*)&sA[0];
  char* const ldsB = (char*)&sB[0];
  const int wb = wid * 1024;

#define GLD(src, dst)                                                          \
  __builtin_amdgcn_global_load_lds(                                            \
      (const __attribute__((address_space(1))) unsigned int*)(src),            \
      (__attribute__((address_space(3))) unsigned int*)(dst), 16, 0, 0)

  for (int k0 = 0; k0 < IN_DIM; k0 += 64) {
    GLD(gA0, ldsA + 0 * 4096 + wb);
    GLD(gA1, ldsA + 1 * 4096 + wb);
    GLD(gA2, ldsA + 2 * 4096 + wb);
    GLD(gA3, ldsA + 3 * 4096 + wb);
    GLD(gB0, ldsB + 0 * 4096 + wb);
    GLD(gB1, ldsB + 1 * 4096 + wb);
    GLD(gB2, ldsB + 2 * 4096 + wb);
    GLD(gB3, ldsB + 3 * 4096 + wb);
    gA0 += 64; gA1 += 64; gA2 += 64; gA3 += 64;
    gB0 += 64; gB1 += 64; gB2 += 64; gB3 += 64;
    __syncthreads();   // vmcnt(0)+lgkmcnt(0) drain, then barrier

#pragma unroll
    for (int kk = 0; kk < 2; ++kk) {
      bf16x8 af[4], bf[4];
      const int kx = ((kk * 4 + kg) ^ (li & 7)) * 8;   // in shorts
#pragma unroll
      for (int m = 0; m < 4; ++m)
        af[m] = *reinterpret_cast<const bf16x8*>(&sA[(wr * 64 + m * 16 + li) * 64 + kx]);
#pragma unroll
      for (int n = 0; n < 4; ++n)
        bf[n] = *reinterpret_cast<const bf16x8*>(&sB[(wc * 64 + n * 16 + li) * 64 + kx]);
#pragma unroll
      for (int m = 0; m < 4; ++m)
#pragma unroll
        for (int n = 0; n < 4; ++n)
          acc[m][n] = __builtin_amdgcn_mfma_f32_16x16x32_bf16(af[m], bf[n], acc[m][n], 0, 0, 0);
    }
    __syncthreads();
  }
#undef GLD

  // epilogue: C/D layout col = lane&15, row = (lane>>4)*4 + j  (m89-verified)
#pragma unroll
  for (int n = 0; n < 4; ++n) {
    const int col = bCol + wc * 64 + n * 16 + li;
    const float bv = bias[col];
#pragma unroll
    for (int m = 0; m < 4; ++m) {
      const int row0 = bRow + wr * 64 + m * 16 + kg * 4;
#pragma unroll
      for (int j = 0; j < 4; ++j)
        Y[(size_t)(row0 + j) * OUT_DIM + col] = acc[m][n][j] + bv;
    }
  }
}

extern "C" void kernel_launch(void* const* d_in, const int* in_sizes, int n_in,
                              void* d_out, int out_size, void* d_ws, size_t ws_size,
                              hipStream_t stream) {
  const float* x    = (const float*)d_in[0];
  const float* w    = (const float*)d_in[1];
  const float* bias = (const float*)d_in[2];
  const float* A    = (const float*)d_in[3];
  const float* B    = (const float*)d_in[4];
  float* y = (float*)d_out;

  const size_t xb_bytes = (size_t)M_DIM * IN_DIM * 2;          // 64 MiB
  const size_t wb_bytes = (size_t)OUT_DIM * IN_DIM * 2;        // 32 MiB
  if (ws_size < xb_bytes + wb_bytes) return;

  unsigned short* Xb = (unsigned short*)d_ws;
  unsigned short* Wb = (unsigned short*)((char*)d_ws + xb_bytes);

  prep_x_kernel<<<2048, 256, 0, stream>>>(x, Xb);
  prep_w_kernel<<<dim3(OUT_DIM / 16, 8), 256, 0, stream>>>(w, A, B, Wb);
  gemm_kernel<<<(M_DIM / 128) * (OUT_DIM / 128), 256, 0, stream>>>(Xb, Wb, bias, y);
}

// Round 3
// 375.734 us; speedup vs baseline: 2.7360x; 2.7360x over previous
//
#include <hip/hip_runtime.h>

#define IN_DIM 4096
#define OUT_DIM 4096
#define M_DIM 8192
#define RANK 32

typedef __bf16 bf16x8 __attribute__((ext_vector_type(8)));
typedef float f32x4 __attribute__((ext_vector_type(4)));

__device__ __forceinline__ unsigned short f2bf(float f) {
  unsigned u = __builtin_bit_cast(unsigned, f);
  u += 0x7FFF + ((u >> 16) & 1);   // round-to-nearest-even
  return (unsigned short)(u >> 16);
}

// ---------------- prep 1: x f32 -> bf16 ----------------
__global__ void prep_x_kernel(const float* __restrict__ X,
                              unsigned short* __restrict__ Xb) {
  const int stride = gridDim.x * blockDim.x;
  const int total4 = (M_DIM * IN_DIM) / 4;
  for (int i = blockIdx.x * blockDim.x + threadIdx.x; i < total4; i += stride) {
    const float4 v = reinterpret_cast<const float4*>(X)[i];
    ushort4 o;
    o.x = f2bf(v.x); o.y = f2bf(v.y); o.z = f2bf(v.z); o.w = f2bf(v.w);
    reinterpret_cast<ushort4*>(Xb)[i] = o;
  }
}

// ---------------- prep 2: Wb = bf16(W + A @ B^T) via rank-32 MFMA ----------------
// Output tile 128(out) x 128(in); delta = A[out][32] . B[in][32]^T -> one
// mfma_f32_16x16x32_bf16 per 16x16 fragment (K=32 exactly). No per-thread
// arrays beyond the 4x4 accumulator -> no scratch spills (round-2 lesson).
__global__ __launch_bounds__(256) void prep_w_kernel(
    const float* __restrict__ W, const float* __restrict__ A,
    const float* __restrict__ B, unsigned short* __restrict__ Wb) {
  __shared__ unsigned short sA[128][40];   // out-tile rows of A, +8 pad (bank-safe)
  __shared__ unsigned short sB[128][40];   // in-tile  rows of B
  const int tid  = threadIdx.x;
  const int lane = tid & 63;
  const int wid  = tid >> 6;
  const int wr   = wid >> 1, wc = wid & 1;
  const int li   = lane & 15, kg = lane >> 4;
  const int bRow = blockIdx.y * 128;   // out dim
  const int bCol = blockIdx.x * 128;   // in dim

  // stage A,B tiles: 128 rows x 32 f32 = 8 float4 per row, cast to bf16
  for (int i = tid; i < 128 * 8; i += 256) {
    const int r = i >> 3, q = i & 7;
    const float4 va = reinterpret_cast<const float4*>(A + (size_t)(bRow + r) * RANK)[q];
    ushort4 oa;
    oa.x = f2bf(va.x); oa.y = f2bf(va.y); oa.z = f2bf(va.z); oa.w = f2bf(va.w);
    *reinterpret_cast<ushort4*>(&sA[r][q * 4]) = oa;
    const float4 vb = reinterpret_cast<const float4*>(B + (size_t)(bCol + r) * RANK)[q];
    ushort4 ob;
    ob.x = f2bf(vb.x); ob.y = f2bf(vb.y); ob.z = f2bf(vb.z); ob.w = f2bf(vb.w);
    *reinterpret_cast<ushort4*>(&sB[r][q * 4]) = ob;
  }
  __syncthreads();

  bf16x8 af[4], bf[4];
#pragma unroll
  for (int m = 0; m < 4; ++m)
    af[m] = *reinterpret_cast<const bf16x8*>(&sA[wr * 64 + m * 16 + li][kg * 8]);
#pragma unroll
  for (int n = 0; n < 4; ++n)
    bf[n] = *reinterpret_cast<const bf16x8*>(&sB[wc * 64 + n * 16 + li][kg * 8]);

  f32x4 acc[4][4];
#pragma unroll
  for (int m = 0; m < 4; ++m)
#pragma unroll
    for (int n = 0; n < 4; ++n) {
      acc[m][n] = f32x4{0.f, 0.f, 0.f, 0.f};
      acc[m][n] = __builtin_amdgcn_mfma_f32_16x16x32_bf16(af[m], bf[n], acc[m][n], 0, 0, 0);
    }

  // epilogue: C/D layout col = li, row = kg*4 + j (m89-verified, same as gemm)
#pragma unroll
  for (int m = 0; m < 4; ++m) {
#pragma unroll
    for (int n = 0; n < 4; ++n) {
      const int col = bCol + wc * 64 + n * 16 + li;
#pragma unroll
      for (int j = 0; j < 4; ++j) {
        const int row = bRow + wr * 64 + m * 16 + kg * 4 + j;
        const size_t idx = (size_t)row * IN_DIM + col;
        Wb[idx] = f2bf(W[idx] + acc[m][n][j]);
      }
    }
  }
}

// ---------------- main GEMM: Y[M][N] = Xb[M][K] * Wb[N][K]^T + bias ----------------
// 128x128 tile, BK=64, 4 waves (2x2), each wave 64x64 via 4x4 frags of 16x16x32 MFMA.
// LDS XOR-swizzle: logical (row, kc) chunk (16B, kc=k>>3) stored at physical
// chunk row*8 + (kc ^ (row&7)); linear gload_lds dest + inverse-swizzled global
// source + swizzled ds_read (rule #21).
__global__ __launch_bounds__(256) void gemm_kernel(
    const unsigned short* __restrict__ Xb, const unsigned short* __restrict__ Wb,
    const float* __restrict__ bias, float* __restrict__ Y) {
  __shared__ unsigned short sA[128 * 64];   // 16 KB
  __shared__ unsigned short sB[128 * 64];   // 16 KB
  const int tid  = threadIdx.x;
  const int lane = tid & 63;
  const int wid  = tid >> 6;
  const int wr   = wid >> 1, wc = wid & 1;
  const int li   = lane & 15, kg = lane >> 4;

  // XCD-aware bijective swizzle: 2048 blocks = 8 XCDs x 256
  const int bid = blockIdx.x;
  const int swz = (bid & 7) * 256 + (bid >> 3);
  const int bx  = swz & 31;    // N tile index (OUT/128 = 32)
  const int by  = swz >> 5;    // M tile index (M/128 = 64)
  const int bRow = by * 128;
  const int bCol = bx * 128;

  f32x4 acc[4][4];
#pragma unroll
  for (int m = 0; m < 4; ++m)
#pragma unroll
    for (int n = 0; n < 4; ++n) acc[m][n] = f32x4{0.f, 0.f, 0.f, 0.f};

  // staging source per thread per slot t: physical chunk p = t*256 + tid,
  // row = p>>3, logical kc = (p&7) ^ (row&7)
  const int p0 = tid, r_0 = p0 >> 3, kc_0 = (p0 & 7) ^ (r_0 & 7);
  const int p1 = 256 + tid, r_1 = p1 >> 3, kc_1 = (p1 & 7) ^ (r_1 & 7);
  const int p2 = 512 + tid, r_2 = p2 >> 3, kc_2 = (p2 & 7) ^ (r_2 & 7);
  const int p3 = 768 + tid, r_3 = p3 >> 3, kc_3 = (p3 & 7) ^ (r_3 & 7);

  const unsigned short* gA0 = Xb + (size_t)(bRow + r_0) * IN_DIM + kc_0 * 8;
  const unsigned short* gA1 = Xb + (size_t)(bRow + r_1) * IN_DIM + kc_1 * 8;
  const unsigned short* gA2 = Xb + (size_t)(bRow + r_2) * IN_DIM + kc_2 * 8;
  const unsigned short* gA3 = Xb + (size_t)(bRow + r_3) * IN_DIM + kc_3 * 8;
  const unsigned short* gB0 = Wb + (size_t)(bCol + r_0) * IN_DIM + kc_0 * 8;
  const unsigned short* gB1 = Wb + (size_t)(bCol + r_1) * IN_DIM + kc_1 * 8;
  const unsigned short* gB2 = Wb + (size_t)(bCol + r_2) * IN_DIM + kc_2 * 8;
  const unsigned short* gB3 = Wb + (size_t)(bCol + r_3) * IN_DIM + kc_3 * 8;

  char* const ldsA = (char*)&sA[0];
  char* const ldsB = (char*)&sB[0];
  const int wb = wid * 1024;

#define GLD(src, dst)                                                          \
  __builtin_amdgcn_global_load_lds(                                            \
      (const __attribute__((address_space(1))) unsigned int*)(src),            \
      (__attribute__((address_space(3))) unsigned int*)(dst), 16, 0, 0)

  for (int k0 = 0; k0 < IN_DIM; k0 += 64) {
    GLD(gA0, ldsA + 0 * 4096 + wb);
    GLD(gA1, ldsA + 1 * 4096 + wb);
    GLD(gA2, ldsA + 2 * 4096 + wb);
    GLD(gA3, ldsA + 3 * 4096 + wb);
    GLD(gB0, ldsB + 0 * 4096 + wb);
    GLD(gB1, ldsB + 1 * 4096 + wb);
    GLD(gB2, ldsB + 2 * 4096 + wb);
    GLD(gB3, ldsB + 3 * 4096 + wb);
    gA0 += 64; gA1 += 64; gA2 += 64; gA3 += 64;
    gB0 += 64; gB1 += 64; gB2 += 64; gB3 += 64;
    __syncthreads();   // vmcnt(0)+lgkmcnt(0) drain, then barrier

#pragma unroll
    for (int kk = 0; kk < 2; ++kk) {
      bf16x8 af[4], bf[4];
      const int kx = ((kk * 4 + kg) ^ (li & 7)) * 8;   // in shorts
#pragma unroll
      for (int m = 0; m < 4; ++m)
        af[m] = *reinterpret_cast<const bf16x8*>(&sA[(wr * 64 + m * 16 + li) * 64 + kx]);
#pragma unroll
      for (int n = 0; n < 4; ++n)
        bf[n] = *reinterpret_cast<const bf16x8*>(&sB[(wc * 64 + n * 16 + li) * 64 + kx]);
#pragma unroll
      for (int m = 0; m < 4; ++m)
#pragma unroll
        for (int n = 0; n < 4; ++n)
          acc[m][n] = __builtin_amdgcn_mfma_f32_16x16x32_bf16(af[m], bf[n], acc[m][n], 0, 0, 0);
    }
    __syncthreads();
  }
#undef GLD

  // epilogue: C/D layout col = lane&15, row = (lane>>4)*4 + j  (m89-verified)
#pragma unroll
  for (int n = 0; n < 4; ++n) {
    const int col = bCol + wc * 64 + n * 16 + li;
    const float bv = bias[col];
#pragma unroll
    for (int m = 0; m < 4; ++m) {
      const int row0 = bRow + wr * 64 + m * 16 + kg * 4;
#pragma unroll
      for (int j = 0; j < 4; ++j)
        Y[(size_t)(row0 + j) * OUT_DIM + col] = acc[m][n][j] + bv;
    }
  }
}

extern "C" void kernel_launch(void* const* d_in, const int* in_sizes, int n_in,
                              void* d_out, int out_size, void* d_ws, size_t ws_size,
                              hipStream_t stream) {
  const float* x    = (const float*)d_in[0];
  const float* w    = (const float*)d_in[1];
  const float* bias = (const float*)d_in[2];
  const float* A    = (const float*)d_in[3];
  const float* B    = (const float*)d_in[4];
  float* y = (float*)d_out;

  const size_t xb_bytes = (size_t)M_DIM * IN_DIM * 2;          // 64 MiB
  const size_t wb_bytes = (size_t)OUT_DIM * IN_DIM * 2;        // 32 MiB
  if (ws_size < xb_bytes + wb_bytes) return;

  unsigned short* Xb = (unsigned short*)d_ws;
  unsigned short* Wb = (unsigned short*)((char*)d_ws + xb_bytes);

  prep_x_kernel<<<2048, 256, 0, stream>>>(x, Xb);
  prep_w_kernel<<<dim3(IN_DIM / 128, OUT_DIM / 128), 256, 0, stream>>>(w, A, B, Wb);
  gemm_kernel<<<(M_DIM / 128) * (OUT_DIM / 128), 256, 0, stream>>>(Xb, Wb, bias, y);
}

// Round 4
// 292.523 us; speedup vs baseline: 3.5142x; 1.2845x over previous
//
#include <hip/hip_runtime.h>

#define IN_DIM 4096
#define OUT_DIM 4096
#define M_DIM 8192
#define RANK 32
#define BK 64
#define NT (IN_DIM / BK)   // 64 K-tiles

typedef __bf16 bf16x8 __attribute__((ext_vector_type(8)));
typedef float f32x4 __attribute__((ext_vector_type(4)));

__device__ __forceinline__ unsigned short f2bf(float f) {
  unsigned u = __builtin_bit_cast(unsigned, f);
  u += 0x7FFF + ((u >> 16) & 1);   // round-to-nearest-even
  return (unsigned short)(u >> 16);
}

// ---------------- prep 1: x f32 -> bf16 ----------------
__global__ void prep_x_kernel(const float* __restrict__ X,
                              unsigned short* __restrict__ Xb) {
  const int stride = gridDim.x * blockDim.x;
  const int total4 = (M_DIM * IN_DIM) / 4;
  for (int i = blockIdx.x * blockDim.x + threadIdx.x; i < total4; i += stride) {
    const float4 v = reinterpret_cast<const float4*>(X)[i];
    ushort4 o;
    o.x = f2bf(v.x); o.y = f2bf(v.y); o.z = f2bf(v.z); o.w = f2bf(v.w);
    reinterpret_cast<ushort4*>(Xb)[i] = o;
  }
}

// ---------------- prep 2: Wb = bf16(W + A @ B^T) via rank-32 MFMA ----------------
__global__ __launch_bounds__(256) void prep_w_kernel(
    const float* __restrict__ W, const float* __restrict__ A,
    const float* __restrict__ B, unsigned short* __restrict__ Wb) {
  __shared__ unsigned short sA[128][40];
  __shared__ unsigned short sB[128][40];
  const int tid  = threadIdx.x;
  const int lane = tid & 63;
  const int wid  = tid >> 6;
  const int wr   = wid >> 1, wc = wid & 1;
  const int li   = lane & 15, kg = lane >> 4;
  const int bRow = blockIdx.y * 128;   // out dim
  const int bCol = blockIdx.x * 128;   // in dim

  for (int i = tid; i < 128 * 8; i += 256) {
    const int r = i >> 3, q = i & 7;
    const float4 va = reinterpret_cast<const float4*>(A + (size_t)(bRow + r) * RANK)[q];
    ushort4 oa;
    oa.x = f2bf(va.x); oa.y = f2bf(va.y); oa.z = f2bf(va.z); oa.w = f2bf(va.w);
    *reinterpret_cast<ushort4*>(&sA[r][q * 4]) = oa;
    const float4 vb = reinterpret_cast<const float4*>(B + (size_t)(bCol + r) * RANK)[q];
    ushort4 ob;
    ob.x = f2bf(vb.x); ob.y = f2bf(vb.y); ob.z = f2bf(vb.z); ob.w = f2bf(vb.w);
    *reinterpret_cast<ushort4*>(&sB[r][q * 4]) = ob;
  }
  __syncthreads();

  bf16x8 af[4], bq[4];
#pragma unroll
  for (int m = 0; m < 4; ++m)
    af[m] = *reinterpret_cast<const bf16x8*>(&sA[wr * 64 + m * 16 + li][kg * 8]);
#pragma unroll
  for (int n = 0; n < 4; ++n)
    bq[n] = *reinterpret_cast<const bf16x8*>(&sB[wc * 64 + n * 16 + li][kg * 8]);

  f32x4 acc[4][4];
#pragma unroll
  for (int m = 0; m < 4; ++m)
#pragma unroll
    for (int n = 0; n < 4; ++n) {
      acc[m][n] = f32x4{0.f, 0.f, 0.f, 0.f};
      acc[m][n] = __builtin_amdgcn_mfma_f32_16x16x32_bf16(af[m], bq[n], acc[m][n], 0, 0, 0);
    }

#pragma unroll
  for (int m = 0; m < 4; ++m) {
#pragma unroll
    for (int n = 0; n < 4; ++n) {
      const int col = bCol + wc * 64 + n * 16 + li;
#pragma unroll
      for (int j = 0; j < 4; ++j) {
        const int row = bRow + wr * 64 + m * 16 + kg * 4 + j;
        const size_t idx = (size_t)row * IN_DIM + col;
        Wb[idx] = f2bf(W[idx] + acc[m][n][j]);
      }
    }
  }
}

// ---------------- main GEMM: 256x256 tile, BK=64, 8-phase counted-vmcnt ----------------
// 8 waves (2M x 4N), per-wave 128x64 output = 8x4 frags of 16x16x32 MFMA.
// LDS 128 KiB: lds[8][8192] shorts; region q = dbuf*4 + op*2 + half (16 KiB each).
// Interleaved half mapping (region death drives WAR-free staging):
//   A half h = tile rows { wr*128 + h*64 .. +63 : wr=0,1 }  (ms=h quadrants)
//   B half h = tile rows { wc*64 + h*32 .. +31 : wc=0..3 }  (ns=h quadrants)
// Within a half: local row r (128), 8 x 16B k-chunks, chunk stored at kc^(r&7).
// Phase schedule per tile t (dbuf d=t&1), template per guide §5:
//   ph0: stage B1(t+1)->d^1 | read A0(8)+B0(4) | BAR | prio MM(0,0) | BAR
//   ph1: stage A0(t+2)->d   | read B1(4)       | BAR | prio MM(0,1) | BAR
//   ph2: stage B0(t+2)->d   | read A1(8)       | BAR | prio MM(1,0) | BAR
//   ph3: stage A1(t+2)->d   |                  | BAR | prio MM(1,1) | vmcnt(6) BAR
// Steady state: 3 half-tiles (6 loads) in flight across the tile boundary.
__global__ __launch_bounds__(512, 2) void gemm_kernel(
    const unsigned short* __restrict__ Xb, const unsigned short* __restrict__ Wb,
    const float* __restrict__ bias, float* __restrict__ Y) {
  __shared__ unsigned short lds[8][8192];   // 128 KiB
  const int tid  = threadIdx.x;
  const int lane = tid & 63;
  const int wid  = tid >> 6;          // 0..7
  const int wr   = wid >> 2;          // 0..1
  const int wc   = wid & 3;           // 0..3
  const int li   = lane & 15, kg = lane >> 4;

  // XCD-aware bijective swizzle: 512 blocks = 8 XCDs x 64
  const int bid = blockIdx.x;
  const int swz = (bid & 7) * 64 + (bid >> 3);
  const int bx  = swz & 15;           // N tiles: 4096/256 = 16
  const int by  = swz >> 4;           // M tiles: 8192/256 = 32
  const int bRow = by * 256, bCol = bx * 256;

  // ---- staging source addresses (per thread, per half h, per sub-load l) ----
  // physical chunk p = l*512 + tid; local row r = p>>3; kc = (p&7)^(r&7)
  const int kcS = (tid & 7) ^ ((tid >> 3) & 7);
  const unsigned short* srcA[2][2];
  const unsigned short* srcB[2][2];
#pragma unroll
  for (int h = 0; h < 2; ++h)
#pragma unroll
    for (int l = 0; l < 2; ++l) {
      const int gA = l * 128 + h * 64 + (tid >> 3);
      const int gB = (l * 2 + (tid >> 8)) * 64 + h * 32 + ((tid >> 3) & 31);
      srcA[h][l] = Xb + (size_t)(bRow + gA) * IN_DIM + kcS * 8;
      srcB[h][l] = Wb + (size_t)(bCol + gB) * IN_DIM + kcS * 8;
    }
  char* const ldsRaw = (char*)&lds[0][0];

#define GLD(src, dstoff)                                                       \
  __builtin_amdgcn_global_load_lds(                                            \
      (const __attribute__((address_space(1))) unsigned int*)(src),            \
      (__attribute__((address_space(3))) unsigned int*)(ldsRaw + (dstoff)),    \
      16, 0, 0)
#define STAGE_A(s, h)                                                          \
  do {                                                                         \
    const int q_ = (((s) & 1) << 2) + (h);                                     \
    GLD(srcA[h][0] + (s) * BK, q_ * 16384 + tid * 16);                         \
    GLD(srcA[h][1] + (s) * BK, q_ * 16384 + 8192 + tid * 16);                  \
  } while (0)
#define STAGE_B(s, h)                                                          \
  do {                                                                         \
    const int q_ = (((s) & 1) << 2) + 2 + (h);                                 \
    GLD(srcB[h][0] + (s) * BK, q_ * 16384 + tid * 16);                         \
    GLD(srcB[h][1] + (s) * BK, q_ * 16384 + 8192 + tid * 16);                  \
  } while (0)
#define BAR() __builtin_amdgcn_s_barrier()

  // ---- fragment read addressing ----
  const int rowAoff = (wr * 64 + li) * 64;
  const int rowBoff = (wc * 32 + li) * 64;
  int kx[2];
  kx[0] = ((0 * 4 + kg) ^ (li & 7)) * 8;
  kx[1] = ((1 * 4 + kg) ^ (li & 7)) * 8;

  bf16x8 af[4][2], bq[4][2];
  f32x4 acc[8][4];
#pragma unroll
  for (int m = 0; m < 8; ++m)
#pragma unroll
    for (int n = 0; n < 4; ++n) acc[m][n] = f32x4{0.f, 0.f, 0.f, 0.f};

#define RD_A(ms_)                                                              \
  do {                                                                         \
    const unsigned short* b_ = &lds[(dcur << 2) + (ms_)][0] + rowAoff;         \
    _Pragma("unroll") for (int mq = 0; mq < 4; ++mq)                           \
      _Pragma("unroll") for (int ks = 0; ks < 2; ++ks)                         \
        af[mq][ks] =                                                           \
            *reinterpret_cast<const bf16x8*>(b_ + mq * 1024 + kx[ks]);         \
  } while (0)
#define RD_B(ns_)                                                              \
  do {                                                                         \
    const unsigned short* b_ = &lds[(dcur << 2) + 2 + (ns_)][0] + rowBoff;     \
    _Pragma("unroll") for (int nq = 0; nq < 2; ++nq)                           \
      _Pragma("unroll") for (int ks = 0; ks < 2; ++ks)                         \
        bq[(ns_) * 2 + nq][ks] =                                               \
            *reinterpret_cast<const bf16x8*>(b_ + nq * 1024 + kx[ks]);         \
  } while (0)
#define MM(ms_, ns_)                                                           \
  do {                                                                         \
    __builtin_amdgcn_s_setprio(1);                                             \
    _Pragma("unroll") for (int mq = 0; mq < 4; ++mq)                           \
      _Pragma("unroll") for (int nq = 0; nq < 2; ++nq)                         \
        _Pragma("unroll") for (int ks = 0; ks < 2; ++ks)                       \
          acc[(ms_) * 4 + mq][(ns_) * 2 + nq] =                                \
              __builtin_amdgcn_mfma_f32_16x16x32_bf16(                         \
                  af[mq][ks], bq[(ns_) * 2 + nq][ks],                          \
                  acc[(ms_) * 4 + mq][(ns_) * 2 + nq], 0, 0, 0);               \
    __builtin_amdgcn_s_setprio(0);                                             \
  } while (0)

  // ---- prologue: tile 0 fully + A0,B0,A1 of tile 1 (B1(1) staged at t=0 ph0)
  STAGE_A(0, 0); STAGE_A(0, 1); STAGE_B(0, 0); STAGE_B(0, 1);
  STAGE_A(1, 0); STAGE_B(1, 0); STAGE_A(1, 1);
  asm volatile("s_waitcnt vmcnt(6)" ::: "memory");   // drain tile 0's 8 loads
  BAR();

  for (int t = 0; t < NT; ++t) {
    const int dcur = t & 1;
    const bool st1 = (t + 1 < NT), st2 = (t + 2 < NT);
    // ph0
    if (st1) STAGE_B(t + 1, 1);
    RD_A(0); RD_B(0);
    BAR();
    MM(0, 0);
    BAR();
    // ph1
    if (st2) STAGE_A(t + 2, 0);
    RD_B(1);
    BAR();
    MM(0, 1);
    BAR();
    // ph2
    if (st2) STAGE_B(t + 2, 0);
    RD_A(1);
    BAR();
    MM(1, 0);
    BAR();
    // ph3
    if (st2) STAGE_A(t + 2, 1);
    BAR();
    MM(1, 1);
    if (st2) asm volatile("s_waitcnt vmcnt(6)" ::: "memory");
    else     asm volatile("s_waitcnt vmcnt(0)" ::: "memory");
    BAR();
  }
#undef GLD
#undef STAGE_A
#undef STAGE_B
#undef RD_A
#undef RD_B
#undef MM
#undef BAR

  // ---- epilogue: C/D layout col = li, row = kg*4 + j (m89-verified) ----
#pragma unroll
  for (int nf = 0; nf < 4; ++nf) {
    const int col = bCol + wc * 64 + nf * 16 + li;
    const float bv = bias[col];
#pragma unroll
    for (int mf = 0; mf < 8; ++mf) {
      const int row0 = bRow + wr * 128 + mf * 16 + kg * 4;
#pragma unroll
      for (int j = 0; j < 4; ++j)
        Y[(size_t)(row0 + j) * OUT_DIM + col] = acc[mf][nf][j] + bv;
    }
  }
}

extern "C" void kernel_launch(void* const* d_in, const int* in_sizes, int n_in,
                              void* d_out, int out_size, void* d_ws, size_t ws_size,
                              hipStream_t stream) {
  const float* x    = (const float*)d_in[0];
  const float* w    = (const float*)d_in[1];
  const float* bias = (const float*)d_in[2];
  const float* A    = (const float*)d_in[3];
  const float* B    = (const float*)d_in[4];
  float* y = (float*)d_out;

  const size_t xb_bytes = (size_t)M_DIM * IN_DIM * 2;          // 64 MiB
  const size_t wb_bytes = (size_t)OUT_DIM * IN_DIM * 2;        // 32 MiB
  if (ws_size < xb_bytes + wb_bytes) return;

  unsigned short* Xb = (unsigned short*)d_ws;
  unsigned short* Wb = (unsigned short*)((char*)d_ws + xb_bytes);

  prep_x_kernel<<<2048, 256, 0, stream>>>(x, Xb);
  prep_w_kernel<<<dim3(IN_DIM / 128, OUT_DIM / 128), 256, 0, stream>>>(w, A, B, Wb);
  gemm_kernel<<<(M_DIM / 256) * (OUT_DIM / 256), 512, 0, stream>>>(Xb, Wb, bias, y);
}